// Round 7
// baseline (86.855 us; speedup 1.0000x reference)
//
#include <hip/hip_runtime.h>

// Helmholtz loss, fully reduced:
//   patch(b,h,w) = w^T H w, w from per-pixel linear fields,
//   H = M^T (a1*C1 + a2*C2 + a3*C3sym) M  (host, double precision).
// Round-7: one-shot, loop-free. One wave = one patch row (512 cols).
// 16 float4 loads/lane (top+bottom rows, 4 ch) -> fields -> quad form.
// No LDS / no barriers / no loops in hot path: nothing for the scheduler
// to sink (r3-r5 failure), no barrier drain (r6 failure). 2x logical row
// reads merge in L2/MSHR (adjacent waves in same block issue together).
// Fused last-block final reduction (proven r3-r6).

struct HParams {
    float u0, u1, u2, u3;
    float H00, H11, H22, H33;
    float H01_2, H02_2, H03_2, H12_2, H13_2, H23_2;
};

#define BSIZE 256
#define NBLK  2048

__device__ __forceinline__ float f4get(const float4& v, int k) {
    switch (k & 3) { case 0: return v.x; case 1: return v.y; case 2: return v.z; default: return v.w; }
}

__global__ __launch_bounds__(BSIZE, 4) void helm_main(const float* __restrict__ x,
                                                      double* __restrict__ partial,
                                                      unsigned int* __restrict__ counter,
                                                      float* __restrict__ out,
                                                      HParams P)
{
    const int t    = threadIdx.x;
    const int lane = t & 63;
    const int w    = t >> 6;               // wave id in block
    const int blk  = blockIdx.x;
    const int b    = blk >> 7;             // image 0..15
    const int win  = blk & 127;            // 4-row window 0..127
    const int rt   = win * 4 + w;          // top data row = patch row, 0..511
    const int rb   = min(rt + 1, 511);     // bottom data row (clamped; rt=511 masked)

    const float4* px = (const float4*)(x + (size_t)b * (4u * 512u * 512u));
    const int cq = lane * 2;               // lane owns cols [8*lane, 8*lane+8)

    // ---- straight-line loads: 2 rows x 4 ch x 2 float4 = 16 loads ----
    float4 T[4][2], B[4][2];
    #pragma unroll
    for (int ch = 0; ch < 4; ++ch) {
        const size_t bt = (size_t)ch * 65536u + (size_t)rt * 128u + (size_t)cq;
        const size_t bb = (size_t)ch * 65536u + (size_t)rb * 128u + (size_t)cq;
        T[ch][0] = px[bt];  T[ch][1] = px[bt + 1];
        B[ch][0] = px[bb];  B[ch][1] = px[bb + 1];
    }

    // ---- per-col patch w-vector components (cols m = 0..7 of this lane) ----
    float aV[8], bV[8], cV[8];
    #pragma unroll
    for (int m = 0; m < 8; ++m) {
        const int g = m >> 2, j = m & 3;
        const float xt0 = f4get(T[0][g], j), xt1 = f4get(T[1][g], j);
        const float xt2 = f4get(T[2][g], j), xt3 = f4get(T[3][g], j);
        const float xb0 = f4get(B[0][g], j), xb1 = f4get(B[1][g], j);
        const float xb2 = f4get(B[2][g], j), xb3 = f4get(B[3][g], j);
        const float t0 = P.u0 * xt0;
        const float F1 = fmaf(P.u2, xt3, t0);
        const float F2 = fmaf(P.u2, xt1, t0);
        const float F4 = fmaf(P.u2, xt3, P.u0 * xt2);
        const float f3 = fmaf(P.u3, xb1, P.u1 * xb0);
        const float f5 = fmaf(P.u3, xb3, P.u1 * xb2);
        aV[m] = F1 + f3;
        bV[m] = F2 + f3;
        cV[m] = F4 + f5;
    }

    // horizontal neighbor (col 8*lane+8) from lane+1
    const float bn = __shfl_down(bV[0], 1, 64);
    const float cn = __shfl_down(cV[0], 1, 64);

    float rowsum = 0.0f;
    #pragma unroll
    for (int m = 0; m < 8; ++m) {
        const float w0 = aV[m];
        const float w1 = (m < 7) ? bV[m + 1] : bn;
        const float w2 = cV[m];
        const float w3 = (m < 7) ? cV[m + 1] : cn;
        const float q0 = fmaf(P.H03_2, w3, fmaf(P.H02_2, w2, fmaf(P.H01_2, w1, P.H00 * w0)));
        const float q1 = fmaf(P.H13_2, w3, fmaf(P.H12_2, w2, P.H11 * w1));
        const float q2 = fmaf(P.H23_2, w3, P.H22 * w2);
        const float q3 = P.H33 * w3;
        const float pq = fmaf(w0, q0, fmaf(w1, q1, fmaf(w2, q2, w3 * q3)));
        rowsum += (m < 7 || lane < 63) ? pq : 0.0f;   // col 511 has no patch
    }
    double acc = (rt < 511) ? (double)rowsum : 0.0;    // row 511 has no patch

    // ---- block reduction + fused final fold ----
    __shared__ double wred[4];
    __shared__ int    isLast;
    #pragma unroll
    for (int off = 32; off > 0; off >>= 1)
        acc += __shfl_down(acc, off, 64);
    if (lane == 0) wred[w] = acc;
    __syncthreads();
    if (t == 0) {
        const double bsum = wred[0] + wred[1] + wred[2] + wred[3];
        __hip_atomic_store(&partial[blk], bsum, __ATOMIC_RELAXED, __HIP_MEMORY_SCOPE_AGENT);
        const unsigned int old = __hip_atomic_fetch_add(counter, 1u, __ATOMIC_ACQ_REL, __HIP_MEMORY_SCOPE_AGENT);
        isLast = (old == (unsigned int)(NBLK - 1)) ? 1 : 0;
    }
    __syncthreads();

    if (isLast) {
        double a = 0.0;
        #pragma unroll
        for (int k = 0; k < NBLK / BSIZE; ++k)
            a += __hip_atomic_load(&partial[t + k * BSIZE], __ATOMIC_RELAXED, __HIP_MEMORY_SCOPE_AGENT);
        #pragma unroll
        for (int off = 32; off > 0; off >>= 1)
            a += __shfl_down(a, off, 64);
        if (lane == 0) wred[w] = a;
        __syncthreads();
        if (t == 0) {
            const double sum = wred[0] + wred[1] + wred[2] + wred[3];
            out[0] = (float)(sum / (16.0 * 511.0 * 511.0));
        }
    }
}

extern "C" void kernel_launch(void* const* d_in, const int* in_sizes, int n_in,
                              void* d_out, int out_size, void* d_ws, size_t ws_size,
                              hipStream_t stream) {
    const float* x  = (const float*)d_in[0];
    float* out      = (float*)d_out;
    double* partial = (double*)d_ws;                                // NBLK doubles
    unsigned int* counter = (unsigned int*)((char*)d_ws + NBLK * sizeof(double));

    // ---- host-side constant computation (double precision) ----
    const double L = 0.01;
    double lm[7];
    lm[0] = L;
    for (int i = 1; i < 7; ++i) lm[i] = lm[i - 1] * L;

    double C1[4][4], C2[4][4] = {}, C3[4][4] = {};
    for (int i = 0; i < 4; ++i)
        for (int j = 0; j < 4; ++j)
            C1[i][j] = lm[i + j] / (double)(i + j + 1);
    C2[2][2] = 4.0 * lm[0];  C2[2][3] = 6.0 * lm[1];
    C2[3][2] = 6.0 * lm[1];  C2[3][3] = 12.0 * lm[2];
    C3[2][0] = 2.0 * lm[0];  C3[2][1] = lm[1];
    C3[2][2] = (2.0 / 3.0) * lm[2];  C3[2][3] = 0.5 * lm[3];
    C3[3][0] = 3.0 * lm[1];  C3[3][1] = 2.0 * lm[2];
    C3[3][2] = 1.5 * lm[3];  C3[3][3] = (6.0 / 5.0) * lm[4];

    const double M[4][4] = {
        {1.0, 0.0, 0.0, 0.0},
        {0.0, 0.0, 1.0, 0.0},
        {-3.0 / lm[1], 3.0 / lm[1], -2.0 / lm[0], -1.0 / lm[0]},
        { 2.0 / lm[2], -2.0 / lm[2], 1.0 / lm[1],  1.0 / lm[1]}
    };

    double s1 = 0.0, s2 = 0.0, s3 = 0.0;
    for (int i = 0; i < 4; ++i)
        for (int j = 0; j < 4; ++j) {
            s1 += C1[i][j]; s2 += C2[i][j]; s3 += C3[i][j];
        }

    const double k2 = 20.0 * 20.0;   // K*K
    const double a1 = s2 + k2 * k2 * s1 + 2.0 * k2 * s3;  // coeff of qC1
    const double a2 = s1;                                 // coeff of qC2
    const double a3 = 2.0 * s3 + 2.0 * k2 * s1;           // coeff of qC3 (+ qC3T == qC3)

    double G[4][4];
    for (int i = 0; i < 4; ++i)
        for (int j = 0; j < 4; ++j)
            G[i][j] = a1 * C1[i][j] + a2 * C2[i][j] + a3 * C3[i][j];

    double H[4][4] = {};
    for (int jj = 0; jj < 4; ++jj)
        for (int kk = 0; kk < 4; ++kk) {
            double s = 0.0;
            for (int a = 0; a < 4; ++a)
                for (int bb = 0; bb < 4; ++bb)
                    s += M[a][jj] * G[a][bb] * M[bb][kk];
            H[jj][kk] = s;
        }
    double Hs[4][4];
    for (int i = 0; i < 4; ++i)
        for (int j = 0; j < 4; ++j)
            Hs[i][j] = 0.5 * (H[i][j] + H[j][i]);

    double u[4];
    for (int j = 0; j < 4; ++j)
        u[j] = M[0][j] + M[1][j] + M[2][j] + M[3][j];

    HParams P;
    P.u0 = (float)u[0]; P.u1 = (float)u[1]; P.u2 = (float)u[2]; P.u3 = (float)u[3];
    P.H00 = (float)Hs[0][0]; P.H11 = (float)Hs[1][1];
    P.H22 = (float)Hs[2][2]; P.H33 = (float)Hs[3][3];
    P.H01_2 = (float)(2.0 * Hs[0][1]); P.H02_2 = (float)(2.0 * Hs[0][2]);
    P.H03_2 = (float)(2.0 * Hs[0][3]); P.H12_2 = (float)(2.0 * Hs[1][2]);
    P.H13_2 = (float)(2.0 * Hs[1][3]); P.H23_2 = (float)(2.0 * Hs[2][3]);

    (void)in_sizes; (void)n_in; (void)out_size; (void)ws_size;

    hipMemsetAsync(counter, 0, sizeof(unsigned int), stream);
    helm_main<<<dim3(NBLK), dim3(BSIZE), 0, stream>>>(x, partial, counter, out, P);
}

// Round 8
// 18.937 us; speedup vs baseline: 4.5865x; 4.5865x over previous
//
#include <hip/hip_runtime.h>

// Helmholtz loss, fully reduced:
//   patch(b,h,w) = w^T H w, w from per-pixel linear fields,
//   H = M^T (a1*C1 + a2*C2 + a3*C3sym) M  (host, double precision).
// Round-8: r2's pipelined register-streaming engine at 2x occupancy,
// NO atomics anywhere (r3-r7 post-mortem: per-block agent-scope acq_rel
// fetch_add serializes ~50ns/block w/ L2 wb/inv on gfx950 -> 2048 blocks
// = ~100us floor). Separate no-atomic reduce kernel (r2-proven, ~3us).
// One wave = 4 patch rows x 512 cols; 5 data rows streamed with 1-row
// lookahead in registers; no LDS / no barriers in hot loop.

struct HParams {
    float u0, u1, u2, u3;
    float H00, H11, H22, H33;
    float H01_2, H02_2, H03_2, H12_2, H13_2, H23_2;
};

#define BSIZE 256
#define NBLK  512

__device__ __forceinline__ float f4get(const float4& v, int k) {
    switch (k & 3) { case 0: return v.x; case 1: return v.y; case 2: return v.z; default: return v.w; }
}

#define LOADROW(B, r) do {                                                      \
    _Pragma("unroll")                                                           \
    for (int ch = 0; ch < 4; ++ch) {                                            \
        const size_t base_ = (size_t)ch * 65536u + (size_t)(r) * 128u + cq;     \
        B[2 * ch]     = px[base_];                                              \
        B[2 * ch + 1] = px[base_ + 1];                                          \
    } } while (0)

#define TOPF(B) do {                                                            \
    _Pragma("unroll")                                                           \
    for (int j = 0; j < 8; ++j) {                                               \
        const float x0_ = f4get(B[0 + (j >> 2)], j);                            \
        const float x1_ = f4get(B[2 + (j >> 2)], j);                            \
        const float x2_ = f4get(B[4 + (j >> 2)], j);                            \
        const float x3_ = f4get(B[6 + (j >> 2)], j);                            \
        const float t0_ = P.u0 * x0_;                                           \
        T1[j] = fmaf(P.u2, x3_, t0_);                                           \
        T2[j] = fmaf(P.u2, x1_, t0_);                                           \
        T4[j] = fmaf(P.u2, x3_, P.u0 * x2_);                                    \
    } } while (0)

__global__ __launch_bounds__(BSIZE, 2) void helm_main(const float* __restrict__ x,
                                                      double* __restrict__ partial,
                                                      HParams P)
{
    const int t    = threadIdx.x;
    const int lane = t & 63;
    const int wid  = t >> 6;
    const int sid  = blockIdx.x * 4 + wid;   // 0..2047 wave-strips
    const int b    = sid >> 7;               // image 0..15
    const int rs   = sid & 127;              // row-strip 0..127
    const int h0   = rs * 4;                 // first patch row (data rows h0..h0+4)

    const float4* px = (const float4*)(x + (size_t)b * (4u * 512u * 512u));
    const int cq = lane * 2;                 // lane owns cols [8*lane, 8*lane+8)

    float4 A[2][8];                          // double-buffered data rows
    float  T1[8], T2[8], T4[8];              // top-role fields of current top row
    double acc = 0.0;

    LOADROW(A[0], h0);
    LOADROW(A[1], h0 + 1);                   // h0+1 <= 509: always valid
    TOPF(A[0]);

    #pragma unroll
    for (int k = 1; k <= 4; ++k) {
        const int cur = k & 1;               // row h0+k lives in A[cur]
        const int nxt = cur ^ 1;
        if (k < 4) {
            const int rn = min(h0 + k + 1, 511);   // only h0+4 can need clamping
            LOADROW(A[nxt], rn);
        }
        // bottom-role fields of row h0+k
        float f3[8], f5[8];
        #pragma unroll
        for (int j = 0; j < 8; ++j) {
            const float x0 = f4get(A[cur][0 + (j >> 2)], j);
            const float x1 = f4get(A[cur][2 + (j >> 2)], j);
            const float x2 = f4get(A[cur][4 + (j >> 2)], j);
            const float x3 = f4get(A[cur][6 + (j >> 2)], j);
            f3[j] = fmaf(P.u3, x1, P.u1 * x0);
            f5[j] = fmaf(P.u3, x3, P.u1 * x2);
        }
        // patch w-vectors for patch row h0+k-1
        float aV[8], bV[8], cV[8];
        #pragma unroll
        for (int j = 0; j < 8; ++j) {
            aV[j] = T1[j] + f3[j];
            bV[j] = T2[j] + f3[j];
            cV[j] = T4[j] + f5[j];
        }
        const float bn = __shfl_down(bV[0], 1, 64);
        const float cn = __shfl_down(cV[0], 1, 64);
        float rowsum = 0.0f;
        #pragma unroll
        for (int j = 0; j < 8; ++j) {
            const float w0 = aV[j];
            const float w1 = (j < 7) ? bV[j + 1] : bn;
            const float w2 = cV[j];
            const float w3 = (j < 7) ? cV[j + 1] : cn;
            const float q0 = fmaf(P.H03_2, w3, fmaf(P.H02_2, w2, fmaf(P.H01_2, w1, P.H00 * w0)));
            const float q1 = fmaf(P.H13_2, w3, fmaf(P.H12_2, w2, P.H11 * w1));
            const float q2 = fmaf(P.H23_2, w3, P.H22 * w2);
            const float q3 = P.H33 * w3;
            const float pq = fmaf(w0, q0, fmaf(w1, q1, fmaf(w2, q2, w3 * q3)));
            rowsum += (j < 7 || lane < 63) ? pq : 0.0f;   // col 511: no patch
        }
        if (h0 + k - 1 < 511)                 // wave-uniform validity (row 511: no patch)
            acc += (double)rowsum;
        // adopt row h0+k's top-role fields
        if (k < 4) TOPF(A[cur]);
    }

    // ---- block reduction, plain store of the partial (no atomics) ----
    __shared__ double wred[4];
    #pragma unroll
    for (int off = 32; off > 0; off >>= 1)
        acc += __shfl_down(acc, off, 64);
    if (lane == 0) wred[wid] = acc;
    __syncthreads();
    if (t == 0)
        partial[blockIdx.x] = wred[0] + wred[1] + wred[2] + wred[3];
}

__global__ __launch_bounds__(BSIZE) void helm_reduce(const double* __restrict__ partial,
                                                     float* __restrict__ out, int n)
{
    __shared__ double wsum[4];
    const int t = threadIdx.x;
    double a = 0.0;
    for (int i = t; i < n; i += BSIZE) a += partial[i];
    #pragma unroll
    for (int off = 32; off > 0; off >>= 1)
        a += __shfl_down(a, off, 64);
    if ((t & 63) == 0) wsum[t >> 6] = a;
    __syncthreads();
    if (t == 0) {
        const double sum = wsum[0] + wsum[1] + wsum[2] + wsum[3];
        out[0] = (float)(sum / (16.0 * 511.0 * 511.0));
    }
}

extern "C" void kernel_launch(void* const* d_in, const int* in_sizes, int n_in,
                              void* d_out, int out_size, void* d_ws, size_t ws_size,
                              hipStream_t stream) {
    const float* x  = (const float*)d_in[0];
    float* out      = (float*)d_out;
    double* partial = (double*)d_ws;     // NBLK doubles = 4 KB

    // ---- host-side constant computation (double precision) ----
    const double L = 0.01;
    double lm[7];
    lm[0] = L;
    for (int i = 1; i < 7; ++i) lm[i] = lm[i - 1] * L;

    double C1[4][4], C2[4][4] = {}, C3[4][4] = {};
    for (int i = 0; i < 4; ++i)
        for (int j = 0; j < 4; ++j)
            C1[i][j] = lm[i + j] / (double)(i + j + 1);
    C2[2][2] = 4.0 * lm[0];  C2[2][3] = 6.0 * lm[1];
    C2[3][2] = 6.0 * lm[1];  C2[3][3] = 12.0 * lm[2];
    C3[2][0] = 2.0 * lm[0];  C3[2][1] = lm[1];
    C3[2][2] = (2.0 / 3.0) * lm[2];  C3[2][3] = 0.5 * lm[3];
    C3[3][0] = 3.0 * lm[1];  C3[3][1] = 2.0 * lm[2];
    C3[3][2] = 1.5 * lm[3];  C3[3][3] = (6.0 / 5.0) * lm[4];

    const double M[4][4] = {
        {1.0, 0.0, 0.0, 0.0},
        {0.0, 0.0, 1.0, 0.0},
        {-3.0 / lm[1], 3.0 / lm[1], -2.0 / lm[0], -1.0 / lm[0]},
        { 2.0 / lm[2], -2.0 / lm[2], 1.0 / lm[1],  1.0 / lm[1]}
    };

    double s1 = 0.0, s2 = 0.0, s3 = 0.0;
    for (int i = 0; i < 4; ++i)
        for (int j = 0; j < 4; ++j) {
            s1 += C1[i][j]; s2 += C2[i][j]; s3 += C3[i][j];
        }

    const double k2 = 20.0 * 20.0;   // K*K
    const double a1 = s2 + k2 * k2 * s1 + 2.0 * k2 * s3;  // coeff of qC1
    const double a2 = s1;                                 // coeff of qC2
    const double a3 = 2.0 * s3 + 2.0 * k2 * s1;           // coeff of qC3 (+ qC3T == qC3)

    double G[4][4];
    for (int i = 0; i < 4; ++i)
        for (int j = 0; j < 4; ++j)
            G[i][j] = a1 * C1[i][j] + a2 * C2[i][j] + a3 * C3[i][j];

    double H[4][4] = {};
    for (int jj = 0; jj < 4; ++jj)
        for (int kk = 0; kk < 4; ++kk) {
            double s = 0.0;
            for (int a = 0; a < 4; ++a)
                for (int bb = 0; bb < 4; ++bb)
                    s += M[a][jj] * G[a][bb] * M[bb][kk];
            H[jj][kk] = s;
        }
    double Hs[4][4];
    for (int i = 0; i < 4; ++i)
        for (int j = 0; j < 4; ++j)
            Hs[i][j] = 0.5 * (H[i][j] + H[j][i]);

    double u[4];
    for (int j = 0; j < 4; ++j)
        u[j] = M[0][j] + M[1][j] + M[2][j] + M[3][j];

    HParams P;
    P.u0 = (float)u[0]; P.u1 = (float)u[1]; P.u2 = (float)u[2]; P.u3 = (float)u[3];
    P.H00 = (float)Hs[0][0]; P.H11 = (float)Hs[1][1];
    P.H22 = (float)Hs[2][2]; P.H33 = (float)Hs[3][3];
    P.H01_2 = (float)(2.0 * Hs[0][1]); P.H02_2 = (float)(2.0 * Hs[0][2]);
    P.H03_2 = (float)(2.0 * Hs[0][3]); P.H12_2 = (float)(2.0 * Hs[1][2]);
    P.H13_2 = (float)(2.0 * Hs[1][3]); P.H23_2 = (float)(2.0 * Hs[2][3]);

    (void)in_sizes; (void)n_in; (void)out_size; (void)ws_size;

    helm_main<<<dim3(NBLK), dim3(BSIZE), 0, stream>>>(x, partial, P);
    helm_reduce<<<dim3(1), dim3(BSIZE), 0, stream>>>(partial, out, NBLK);
}